// Round 13
// baseline (139.477 us; speedup 1.0000x reference)
//
#include <hip/hip_runtime.h>
#include <hip/hip_fp16.h>

typedef __attribute__((ext_vector_type(8))) _Float16 f16x8;
typedef __attribute__((ext_vector_type(4))) float f32x4;
typedef __attribute__((ext_vector_type(4))) unsigned int u32x4;

__device__ __forceinline__ unsigned short f2h(float f) {
  __half h = __float2half(f);
  return __builtin_bit_cast(unsigned short, h);
}
__device__ __forceinline__ __half2 bc_h2(unsigned u) {
  return __builtin_bit_cast(__half2, u);
}

// ---------------------------------------------------------------------------
// Kernel A: prep. blocks 0..511: x NCHW fp32 -> NHWC fp16 xt[b][h][w][c].
// blocks 512..871: repack main_w -> wt[k][128][64], offset_w -> wot[k][32][64].
// ---------------------------------------------------------------------------
__global__ __launch_bounds__(256) void prep_all(
    const float* __restrict__ x, const float* __restrict__ mw,
    const float* __restrict__ ow, unsigned short* __restrict__ xt,
    unsigned short* __restrict__ wt, unsigned short* __restrict__ wot) {
  __shared__ float tile[64 * 129];
  int blk = blockIdx.x;
  int t = threadIdx.x;
  if (blk < 512) {
    const float* xrow = x + ((long)(blk >> 7) << 20) + ((blk & 127) << 7);
#pragma unroll
    for (int i = 0; i < 32; ++i) {
      int idx = t + (i << 8);          // c = idx>>7, w = idx&127
      tile[(idx >> 7) * 129 + (idx & 127)] =
          xrow[((long)(idx >> 7) << 14) + (idx & 127)];
    }
    __syncthreads();
    unsigned short* orow = xt + ((long)blk << 13);
#pragma unroll
    for (int i = 0; i < 32; ++i) {
      int idx = t + (i << 8);          // w = idx>>6, c = idx&63
      orow[idx] = f2h(tile[(idx & 63) * 129 + (idx >> 6)]);
    }
  } else {
    int idx = (blk - 512) * 256 + t;   // 0..92159
    if (idx < 73728) {
      int c = idx & 63;
      int o = (idx >> 6) & 127;
      int k = idx >> 13;
      wt[idx] = f2h(mw[o * 576 + c * 9 + k]);
    } else {
      int i2 = idx - 73728;
      int c = i2 & 63;
      int o = (i2 >> 6) & 31;
      int k = i2 >> 11;
      wot[i2] = (o < 18) ? f2h(ow[o * 576 + c * 9 + k]) : (unsigned short)0;
    }
  }
}

// ---------------------------------------------------------------------------
// Kernel B: offset conv 64->18 via f16 MFMA (64-px blocks, grid 1024).
// ---------------------------------------------------------------------------
__global__ __launch_bounds__(256) void offs_mfma(
    const unsigned short* __restrict__ xt, const unsigned short* __restrict__ wot,
    const float* __restrict__ ob, float* __restrict__ offs) {
  int l = blockIdx.x;
  int bid = ((l & 7) << 7) + (l >> 3);   // XCD swizzle
  int b = bid >> 8;
  int r8 = bid & 255;
  int h = r8 >> 1;
  int w0 = (r8 & 1) << 6;
  int t = threadIdx.x;
  int lane = t & 63;
  int wv = t >> 6;
  int l15 = lane & 15;
  int l4 = lane >> 4;
  int l4k = l4 << 3;

  f32x4 oacc[2];
  oacc[0] = f32x4{0.f, 0.f, 0.f, 0.f};
  oacc[1] = f32x4{0.f, 0.f, 0.f, 0.f};

  const unsigned short* xb = xt + ((long)b << 20);
  const unsigned short* wkb = wot + (l15 << 6) + l4k;

#pragma unroll 1
  for (int k = 0; k < 9; ++k) {
    int ky = k / 3, kx = k - 3 * ky;
    int y = h + ky - 1;
    bool yok = (unsigned)y < 128u;
    int yc = min(max(y, 0), 127);
    const unsigned short* xrow = xb + ((long)yc << 13);
    int px = w0 + (wv << 4) + l15 + kx - 1;
    bool pv = yok && ((unsigned)px < 128u);
    int pxo = min(max(px, 0), 127) << 6;
#pragma unroll
    for (int c0 = 0; c0 < 64; c0 += 32) {
      f16x8 bv = *(const f16x8*)(xrow + pxo + c0 + l4k);
      if (!pv) bv = f16x8{0, 0, 0, 0, 0, 0, 0, 0};
#pragma unroll
      for (int m = 0; m < 2; ++m) {
        f16x8 af = *(const f16x8*)(wkb + (k << 11) + (m << 10) + c0);
        oacc[m] = __builtin_amdgcn_mfma_f32_16x16x32_f16(af, bv, oacc[m], 0, 0, 0);
      }
    }
  }

#pragma unroll
  for (int m = 0; m < 2; ++m) {
#pragma unroll
    for (int r = 0; r < 4; ++r) {
      int oc = (m << 4) + (l4 << 2) + r;
      if (oc < 18)
        offs[((long)(b * 18 + oc) << 14) + (h << 7) + w0 + (wv << 4) + l15] =
            oacc[m][r] + ob[oc];
    }
  }
}

// ---------------------------------------------------------------------------
// Kernel C: deformable conv, register-resident V, NAMED-register 2-stage
// pipeline (no arrays through lambdas -> no scratch; r10 redo).
// Block = 64-px half-row, 4 waves, grid 1024. Wave wv owns px column
// [w0+wv*16,+16) x ALL 128 out-ch (8 m-frags, 1 n-frag). Lane (l15=px,
// l4=8ch chunk) gathers its own B-fragment corners. Fully unrolled 9-tap
// loop; issue tap k+1's 8 loads (older-first vmcnt => counted waits) before
// consuming tap k. Zero barriers after wtab. LDS: 9 KB wtab only.
// ---------------------------------------------------------------------------
#define GISSUE(K, P)                                                        \
  {                                                                         \
    uint4 e_ = wtab[K][pxf];                                                \
    ge##P = e_;                                                             \
    int y0_ = (int)(short)(e_.z & 0xffff), y1_ = (int)(short)(e_.z >> 16);  \
    int x0_ = (int)(short)(e_.w & 0xffff), x1_ = (int)(short)(e_.w >> 16);  \
    const unsigned short* r0_ = xb + (y0_ << 13) + l4k;                     \
    const unsigned short* r1_ = xb + (y1_ << 13) + l4k;                     \
    int o0_ = x0_ << 6, o1_ = x1_ << 6;                                     \
    g##P##0 = *(const u32x4*)(r0_ + o0_);                                   \
    g##P##1 = *(const u32x4*)(r0_ + o1_);                                   \
    g##P##2 = *(const u32x4*)(r1_ + o0_);                                   \
    g##P##3 = *(const u32x4*)(r1_ + o1_);                                   \
    g##P##4 = *(const u32x4*)(r0_ + o0_ + 32);                              \
    g##P##5 = *(const u32x4*)(r0_ + o1_ + 32);                              \
    g##P##6 = *(const u32x4*)(r1_ + o0_ + 32);                              \
    g##P##7 = *(const u32x4*)(r1_ + o1_ + 32);                              \
  }

#define GCONSUME(K, P)                                                      \
  {                                                                         \
    uint4 e_ = ge##P;                                                       \
    __half2 w00_ = bc_h2((e_.x & 0xffffu) | (e_.x << 16));                  \
    __half2 w01_ = bc_h2((e_.x >> 16) | (e_.x & 0xffff0000u));              \
    __half2 w10_ = bc_h2((e_.y & 0xffffu) | (e_.y << 16));                  \
    __half2 w11_ = bc_h2((e_.y >> 16) | (e_.y & 0xffff0000u));              \
    u32x4 rr0_, rr1_;                                                       \
    _Pragma("unroll") for (int j = 0; j < 4; ++j) {                         \
      __half2 v_ = __hmul2(w00_, bc_h2(g##P##0[j]));                        \
      v_ = __hfma2(w01_, bc_h2(g##P##1[j]), v_);                            \
      v_ = __hfma2(w10_, bc_h2(g##P##2[j]), v_);                            \
      v_ = __hfma2(w11_, bc_h2(g##P##3[j]), v_);                            \
      rr0_[j] = __builtin_bit_cast(unsigned, v_);                           \
      __half2 u_ = __hmul2(w00_, bc_h2(g##P##4[j]));                        \
      u_ = __hfma2(w01_, bc_h2(g##P##5[j]), u_);                            \
      u_ = __hfma2(w10_, bc_h2(g##P##6[j]), u_);                            \
      u_ = __hfma2(w11_, bc_h2(g##P##7[j]), u_);                            \
      rr1_[j] = __builtin_bit_cast(unsigned, u_);                           \
    }                                                                       \
    f16x8 bv0_ = __builtin_bit_cast(f16x8, rr0_);                           \
    f16x8 bv1_ = __builtin_bit_cast(f16x8, rr1_);                           \
    const unsigned short* wk_ = wt + ((((K) << 7) + l15) << 6) + l4k;       \
    _Pragma("unroll") for (int m = 0; m < 8; ++m) {                         \
      f16x8 af_ = *(const f16x8*)(wk_ + (m << 10));                         \
      acc[m] = __builtin_amdgcn_mfma_f32_16x16x32_f16(af_, bv0_, acc[m],    \
                                                      0, 0, 0);             \
    }                                                                       \
    _Pragma("unroll") for (int m = 0; m < 8; ++m) {                         \
      f16x8 af_ = *(const f16x8*)(wk_ + (m << 10) + 32);                    \
      acc[m] = __builtin_amdgcn_mfma_f32_16x16x32_f16(af_, bv1_, acc[m],    \
                                                      0, 0, 0);             \
    }                                                                       \
  }

__global__ __launch_bounds__(256) void deform_mfma(
    const unsigned short* __restrict__ xt, const float* __restrict__ offs,
    const unsigned short* __restrict__ wt, const float* __restrict__ mb,
    float* __restrict__ out) {
  __shared__ uint4 wtab[9][64];

  int l = blockIdx.x;
  int bid = ((l & 7) << 7) + (l >> 3);   // XCD swizzle
  int b = bid >> 8;
  int r8 = bid & 255;
  int h = r8 >> 1;
  int w0 = (r8 & 1) << 6;
  int t = threadIdx.x;
  int lane = t & 63;
  int wv = t >> 6;
  int l15 = lane & 15;
  int l4 = lane >> 4;
  int l4k = l4 << 3;
  int pxf = (wv << 4) + l15;             // px-in-tile this lane serves

  // ---- sampling table: 576 = 9 taps x 64 px (one barrier) ----
  const float* ob_ = offs + ((long)(b * 18) << 14) + (h << 7) + w0;
  for (int idx = t; idx < 576; idx += 256) {
    int px = idx & 63, k = idx >> 6;
    int ky = k / 3, kx = k - 3 * ky;
    float dy = ob_[((2 * k) << 14) + px];
    float dx = ob_[((2 * k + 1) << 14) + px];
    float py = (float)(h - 1 + ky) + dy;
    float pxq = (float)(w0 + px - 1 + kx) + dx;
    float fy = floorf(py), fx = floorf(pxq);
    float wy = py - fy, wx = pxq - fx;
    int y0 = (int)fy, x0 = (int)fx;
    int y1 = y0 + 1, x1 = x0 + 1;
    bool vy0 = (unsigned)y0 < 128u, vy1 = (unsigned)y1 < 128u;
    bool vx0 = (unsigned)x0 < 128u, vx1 = (unsigned)x1 < 128u;
    float w00 = (vy0 && vx0) ? (1.f - wy) * (1.f - wx) : 0.f;
    float w01 = (vy0 && vx1) ? (1.f - wy) * wx : 0.f;
    float w10 = (vy1 && vx0) ? wy * (1.f - wx) : 0.f;
    float w11 = (vy1 && vx1) ? wy * wx : 0.f;
    int y0c = min(max(y0, 0), 127), y1c = min(max(y1, 0), 127);
    int x0c = min(max(x0, 0), 127), x1c = min(max(x1, 0), 127);
    wtab[k][px] = make_uint4(
        (unsigned)f2h(w00) | ((unsigned)f2h(w01) << 16),
        (unsigned)f2h(w10) | ((unsigned)f2h(w11) << 16),
        (unsigned)(unsigned short)y0c | ((unsigned)(unsigned short)y1c << 16),
        (unsigned)(unsigned short)x0c | ((unsigned)(unsigned short)x1c << 16));
  }
  __syncthreads();

  const unsigned short* xb = xt + ((long)b << 20);

  f32x4 acc[8];
#pragma unroll
  for (int m = 0; m < 8; ++m) acc[m] = f32x4{0.f, 0.f, 0.f, 0.f};

  u32x4 gA0, gA1, gA2, gA3, gA4, gA5, gA6, gA7;
  u32x4 gB0, gB1, gB2, gB3, gB4, gB5, gB6, gB7;
  uint4 geA, geB;

  GISSUE(0, A)
  GISSUE(1, B) GCONSUME(0, A)
  GISSUE(2, A) GCONSUME(1, B)
  GISSUE(3, B) GCONSUME(2, A)
  GISSUE(4, A) GCONSUME(3, B)
  GISSUE(5, B) GCONSUME(4, A)
  GISSUE(6, A) GCONSUME(5, B)
  GISSUE(7, B) GCONSUME(6, A)
  GISSUE(8, A) GCONSUME(7, B)
  GCONSUME(8, A)

  // ---- epilogue: D row = o (lane>>4)*4+reg, col = px (lane&15) ----
  int hw0 = (h << 7) + w0 + (wv << 4);
#pragma unroll
  for (int m = 0; m < 8; ++m) {
    int orow = (m << 4) + (l4 << 2);
#pragma unroll
    for (int r = 0; r < 4; ++r)
      out[((long)(b * 128 + orow + r) << 14) + hw0 + l15] =
          acc[m][r] + mb[orow + r];
  }
}

extern "C" void kernel_launch(void* const* d_in, const int* in_sizes, int n_in,
                              void* d_out, int out_size, void* d_ws, size_t ws_size,
                              hipStream_t stream) {
  const float* x  = (const float*)d_in[0];
  const float* ow = (const float*)d_in[1];
  const float* ob = (const float*)d_in[2];
  const float* mw = (const float*)d_in[3];
  const float* mb = (const float*)d_in[4];
  float* out  = (float*)d_out;
  unsigned short* xt  = (unsigned short*)d_ws;                      // 8 MB
  unsigned short* wt  = (unsigned short*)((char*)d_ws + 8388608);   // 144 KB
  unsigned short* wot = (unsigned short*)((char*)d_ws + 8536064);   // 36 KB
  float* offs = (float*)((char*)d_ws + 8572928);                    // 4.5 MB

  prep_all<<<872, 256, 0, stream>>>(x, mw, ow, xt, wt, wot);
  offs_mfma<<<1024, 256, 0, stream>>>(xt, wot, ob, offs);
  deform_mfma<<<1024, 256, 0, stream>>>(xt, offs, wt, mb, out);
}

// Round 14
// 85.263 us; speedup vs baseline: 1.6359x; 1.6359x over previous
//
#include <hip/hip_runtime.h>
#include <hip/hip_fp16.h>

typedef __attribute__((ext_vector_type(8))) _Float16 f16x8;
typedef __attribute__((ext_vector_type(4))) float f32x4;
typedef __attribute__((ext_vector_type(4))) unsigned int u32x4;

__device__ __forceinline__ unsigned short f2h(float f) {
  __half h = __float2half(f);
  return __builtin_bit_cast(unsigned short, h);
}
__device__ __forceinline__ __half2 bc_h2(unsigned u) {
  return __builtin_bit_cast(__half2, u);
}

// ---------------------------------------------------------------------------
// Kernel A: prep. blocks 0..511: x NCHW fp32 -> NHWC fp16 xt[b][h][w][c].
// blocks 512..871: repack main_w -> wt[k][128][64], offset_w -> wot[k][32][64].
// ---------------------------------------------------------------------------
__global__ __launch_bounds__(256) void prep_all(
    const float* __restrict__ x, const float* __restrict__ mw,
    const float* __restrict__ ow, unsigned short* __restrict__ xt,
    unsigned short* __restrict__ wt, unsigned short* __restrict__ wot) {
  __shared__ float tile[64 * 129];
  int blk = blockIdx.x;
  int t = threadIdx.x;
  if (blk < 512) {
    const float* xrow = x + ((long)(blk >> 7) << 20) + ((blk & 127) << 7);
#pragma unroll
    for (int i = 0; i < 32; ++i) {
      int idx = t + (i << 8);          // c = idx>>7, w = idx&127
      tile[(idx >> 7) * 129 + (idx & 127)] =
          xrow[((long)(idx >> 7) << 14) + (idx & 127)];
    }
    __syncthreads();
    unsigned short* orow = xt + ((long)blk << 13);
#pragma unroll
    for (int i = 0; i < 32; ++i) {
      int idx = t + (i << 8);          // w = idx>>6, c = idx&63
      orow[idx] = f2h(tile[(idx & 63) * 129 + (idx >> 6)]);
    }
  } else {
    int idx = (blk - 512) * 256 + t;   // 0..92159
    if (idx < 73728) {
      int c = idx & 63;
      int o = (idx >> 6) & 127;
      int k = idx >> 13;
      wt[idx] = f2h(mw[o * 576 + c * 9 + k]);
    } else {
      int i2 = idx - 73728;
      int c = i2 & 63;
      int o = (i2 >> 6) & 31;
      int k = i2 >> 11;
      wot[i2] = (o < 18) ? f2h(ow[o * 576 + c * 9 + k]) : (unsigned short)0;
    }
  }
}

// ---------------------------------------------------------------------------
// Kernel B: offset conv 64->18 via f16 MFMA (64-px blocks, grid 1024).
// ---------------------------------------------------------------------------
__global__ __launch_bounds__(256) void offs_mfma(
    const unsigned short* __restrict__ xt, const unsigned short* __restrict__ wot,
    const float* __restrict__ ob, float* __restrict__ offs) {
  int l = blockIdx.x;
  int bid = ((l & 7) << 7) + (l >> 3);   // XCD swizzle
  int b = bid >> 8;
  int r8 = bid & 255;
  int h = r8 >> 1;
  int w0 = (r8 & 1) << 6;
  int t = threadIdx.x;
  int lane = t & 63;
  int wv = t >> 6;
  int l15 = lane & 15;
  int l4 = lane >> 4;
  int l4k = l4 << 3;

  f32x4 oacc[2];
  oacc[0] = f32x4{0.f, 0.f, 0.f, 0.f};
  oacc[1] = f32x4{0.f, 0.f, 0.f, 0.f};

  const unsigned short* xb = xt + ((long)b << 20);
  const unsigned short* wkb = wot + (l15 << 6) + l4k;

#pragma unroll 1
  for (int k = 0; k < 9; ++k) {
    int ky = k / 3, kx = k - 3 * ky;
    int y = h + ky - 1;
    bool yok = (unsigned)y < 128u;
    int yc = min(max(y, 0), 127);
    const unsigned short* xrow = xb + ((long)yc << 13);
    int px = w0 + (wv << 4) + l15 + kx - 1;
    bool pv = yok && ((unsigned)px < 128u);
    int pxo = min(max(px, 0), 127) << 6;
#pragma unroll
    for (int c0 = 0; c0 < 64; c0 += 32) {
      f16x8 bv = *(const f16x8*)(xrow + pxo + c0 + l4k);
      if (!pv) bv = f16x8{0, 0, 0, 0, 0, 0, 0, 0};
#pragma unroll
      for (int m = 0; m < 2; ++m) {
        f16x8 af = *(const f16x8*)(wkb + (k << 11) + (m << 10) + c0);
        oacc[m] = __builtin_amdgcn_mfma_f32_16x16x32_f16(af, bv, oacc[m], 0, 0, 0);
      }
    }
  }

#pragma unroll
  for (int m = 0; m < 2; ++m) {
#pragma unroll
    for (int r = 0; r < 4; ++r) {
      int oc = (m << 4) + (l4 << 2) + r;
      if (oc < 18)
        offs[((long)(b * 18 + oc) << 14) + (h << 7) + w0 + (wv << 4) + l15] =
            oacc[m][r] + ob[oc];
    }
  }
}

// ---------------------------------------------------------------------------
// Kernel C: deformable conv, depth-2 gather pipeline (r12 + deeper in-flight).
// Block = 64-px half-row, 4 waves, grid 1024. Wave wv = disjoint o-quarter
// (2 m-frags) x all 64 px (4 n-frags). Per iter k:
//   af(k) loads -> ISSUE gathers(k+2) into named reg set -> sched_barrier ->
//   MFMA(k) [af wait = counted vmcnt, gathers stay in flight] ->
//   FINISH(k+1): bilinear + ds_write other buffer [counted vmcnt] ->
//   lgkmcnt(0) + RAW s_barrier (no vmcnt drain -> k+2 gathers survive).
// LDS: 9.2K wtab + 2x9.2K vlds = 27.6 KB.
// ---------------------------------------------------------------------------
#define SB __builtin_amdgcn_sched_barrier(0)
#define BAR                                              \
  {                                                      \
    SB;                                                  \
    asm volatile("s_waitcnt lgkmcnt(0)" ::: "memory");   \
    __builtin_amdgcn_s_barrier();                        \
    SB;                                                  \
  }

#define AF(K)                                                              \
  _Pragma("unroll") for (int c0 = 0; c0 < 2; ++c0)                         \
  _Pragma("unroll") for (int m = 0; m < 2; ++m)                            \
      af[c0][m] = *(const f16x8*)(wkb + ((K) << 13) + (m << 10) + (c0 << 5));

#define ISSUE1(K, S, U, SPX)                                               \
  {                                                                        \
    uint4 e_ = wtab[K][SPX];                                               \
    int y0_ = (int)(short)(e_.z & 0xffff), y1_ = (int)(short)(e_.z >> 16); \
    int x0_ = (int)(short)(e_.w & 0xffff), x1_ = (int)(short)(e_.w >> 16); \
    const unsigned short* r0_ = xb + (y0_ << 13) + sco;                    \
    const unsigned short* r1_ = xb + (y1_ << 13) + sco;                    \
    S##U##0 = *(const u32x4*)(r0_ + (x0_ << 6));                           \
    S##U##1 = *(const u32x4*)(r0_ + (x1_ << 6));                           \
    S##U##2 = *(const u32x4*)(r1_ + (x0_ << 6));                           \
    S##U##3 = *(const u32x4*)(r1_ + (x1_ << 6));                           \
  }

#define ISSUE(K, S) ISSUE1(K, S, 0, spx0) ISSUE1(K, S, 1, (spx0 + 32))

#define FIN1(K, S, U, SPX, BUF)                                            \
  {                                                                        \
    uint4 e_ = wtab[K][SPX];                                               \
    __half2 w00_ = bc_h2((e_.x & 0xffffu) | (e_.x << 16));                 \
    __half2 w01_ = bc_h2((e_.x >> 16) | (e_.x & 0xffff0000u));             \
    __half2 w10_ = bc_h2((e_.y & 0xffffu) | (e_.y << 16));                 \
    __half2 w11_ = bc_h2((e_.y >> 16) | (e_.y & 0xffff0000u));             \
    u32x4 rr_;                                                             \
    _Pragma("unroll") for (int j = 0; j < 4; ++j) {                        \
      __half2 v_ = __hmul2(w00_, bc_h2(S##U##0[j]));                       \
      v_ = __hfma2(w01_, bc_h2(S##U##1[j]), v_);                           \
      v_ = __hfma2(w10_, bc_h2(S##U##2[j]), v_);                           \
      v_ = __hfma2(w11_, bc_h2(S##U##3[j]), v_);                           \
      rr_[j] = __builtin_bit_cast(unsigned, v_);                           \
    }                                                                      \
    *(u32x4*)&BUF[(SPX)*72 + sco] = rr_;                                   \
  }

#define FINISH(K, S, BUF) FIN1(K, S, 0, spx0, BUF) FIN1(K, S, 1, (spx0 + 32), BUF)

#define MFMAP(K, BUF)                                                      \
  _Pragma("unroll") for (int c0 = 0; c0 < 2; ++c0) {                       \
    f16x8 bfr[4];                                                          \
    _Pragma("unroll") for (int n = 0; n < 4; ++n)                          \
        bfr[n] = *(const f16x8*)&BUF[((n << 4) + l15) * 72 + (c0 << 5) + l4k]; \
    _Pragma("unroll") for (int m = 0; m < 2; ++m)                          \
    _Pragma("unroll") for (int n = 0; n < 4; ++n)                          \
        acc[m][n] = __builtin_amdgcn_mfma_f32_16x16x32_f16(                \
            af[c0][m], bfr[n], acc[m][n], 0, 0, 0);                        \
  }

__global__ __launch_bounds__(256, 4) void deform_mfma(
    const unsigned short* __restrict__ xt, const float* __restrict__ offs,
    const unsigned short* __restrict__ wt, const float* __restrict__ mb,
    float* __restrict__ out) {
  __shared__ uint4 wtab[9][64];
  __shared__ unsigned short vlds[2][64 * 72];

  int l = blockIdx.x;
  int bid = ((l & 7) << 7) + (l >> 3);   // XCD swizzle
  int b = bid >> 8;
  int r8 = bid & 255;
  int h = r8 >> 1;
  int w0 = (r8 & 1) << 6;
  int t = threadIdx.x;
  int lane = t & 63;
  int wv = t >> 6;
  int wo = wv << 5;                      // disjoint o-quarter per wave
  int l15 = lane & 15;
  int l4 = lane >> 4;
  int l4k = l4 << 3;

  // ---- sampling table: 576 = 9 taps x 64 px ----
  const float* ob_ = offs + ((long)(b * 18) << 14) + (h << 7) + w0;
  for (int idx = t; idx < 576; idx += 256) {
    int px = idx & 63, k = idx >> 6;
    int ky = k / 3, kx = k - 3 * ky;
    float dy = ob_[((2 * k) << 14) + px];
    float dx = ob_[((2 * k + 1) << 14) + px];
    float py = (float)(h - 1 + ky) + dy;
    float pxf = (float)(w0 + px - 1 + kx) + dx;
    float fy = floorf(py), fx = floorf(pxf);
    float wy = py - fy, wx = pxf - fx;
    int y0 = (int)fy, x0 = (int)fx;
    int y1 = y0 + 1, x1 = x0 + 1;
    bool vy0 = (unsigned)y0 < 128u, vy1 = (unsigned)y1 < 128u;
    bool vx0 = (unsigned)x0 < 128u, vx1 = (unsigned)x1 < 128u;
    float w00 = (vy0 && vx0) ? (1.f - wy) * (1.f - wx) : 0.f;
    float w01 = (vy0 && vx1) ? (1.f - wy) * wx : 0.f;
    float w10 = (vy1 && vx0) ? wy * (1.f - wx) : 0.f;
    float w11 = (vy1 && vx1) ? wy * wx : 0.f;
    int y0c = min(max(y0, 0), 127), y1c = min(max(y1, 0), 127);
    int x0c = min(max(x0, 0), 127), x1c = min(max(x1, 0), 127);
    wtab[k][px] = make_uint4(
        (unsigned)f2h(w00) | ((unsigned)f2h(w01) << 16),
        (unsigned)f2h(w10) | ((unsigned)f2h(w11) << 16),
        (unsigned)(unsigned short)y0c | ((unsigned)(unsigned short)y1c << 16),
        (unsigned)(unsigned short)x0c | ((unsigned)(unsigned short)x1c << 16));
  }
  __syncthreads();                       // wtab ready (one full barrier)

  const unsigned short* xb = xt + ((long)b << 20);
  const unsigned short* wkb = wt + ((wo + l15) << 6) + l4k;
  int spx0 = t >> 3;                     // px unit 0 (unit 1 = +32)
  int sco = (t & 7) << 3;                // 8-ch chunk offset

  f32x4 acc[2][4];
#pragma unroll
  for (int m = 0; m < 2; ++m)
#pragma unroll
    for (int n = 0; n < 4; ++n) acc[m][n] = f32x4{0.f, 0.f, 0.f, 0.f};

  f16x8 af[2][2];
  u32x4 sA00, sA01, sA02, sA03, sA10, sA11, sA12, sA13;
  u32x4 sB00, sB01, sB02, sB03, sB10, sB11, sB12, sB13;

  // ---- prologue: gathers for taps 0 (A) and 1 (B); finish 0 -> buf0 ----
  ISSUE(0, sA)
  ISSUE(1, sB)
  FINISH(0, sA, vlds[0])
  BAR

  // ---- 9-step pipeline: ISSUE(k+2) / MFMA(k) / FINISH(k+1) ----
  AF(0) ISSUE(2, sA) SB; MFMAP(0, vlds[0]) FINISH(1, sB, vlds[1]) BAR
  AF(1) ISSUE(3, sB) SB; MFMAP(1, vlds[1]) FINISH(2, sA, vlds[0]) BAR
  AF(2) ISSUE(4, sA) SB; MFMAP(2, vlds[0]) FINISH(3, sB, vlds[1]) BAR
  AF(3) ISSUE(5, sB) SB; MFMAP(3, vlds[1]) FINISH(4, sA, vlds[0]) BAR
  AF(4) ISSUE(6, sA) SB; MFMAP(4, vlds[0]) FINISH(5, sB, vlds[1]) BAR
  AF(5) ISSUE(7, sB) SB; MFMAP(5, vlds[1]) FINISH(6, sA, vlds[0]) BAR
  AF(6) ISSUE(8, sA) SB; MFMAP(6, vlds[0]) FINISH(7, sB, vlds[1]) BAR
  AF(7)              SB; MFMAP(7, vlds[1]) FINISH(8, sA, vlds[0]) BAR
  AF(8)                  MFMAP(8, vlds[0])

  // ---- epilogue: D row = o (lane>>4)*4+reg, col = px (lane&15) ----
  int hw0 = (h << 7) + w0;
#pragma unroll
  for (int m = 0; m < 2; ++m) {
    int orow = wo + (m << 4) + (l4 << 2);
#pragma unroll
    for (int r = 0; r < 4; ++r) {
      float bias = mb[orow + r];
      long ob2 = ((long)(b * 128 + orow + r) << 14) + hw0;
#pragma unroll
      for (int n = 0; n < 4; ++n)
        out[ob2 + (n << 4) + l15] = acc[m][n][r] + bias;
    }
  }
}

extern "C" void kernel_launch(void* const* d_in, const int* in_sizes, int n_in,
                              void* d_out, int out_size, void* d_ws, size_t ws_size,
                              hipStream_t stream) {
  const float* x  = (const float*)d_in[0];
  const float* ow = (const float*)d_in[1];
  const float* ob = (const float*)d_in[2];
  const float* mw = (const float*)d_in[3];
  const float* mb = (const float*)d_in[4];
  float* out  = (float*)d_out;
  unsigned short* xt  = (unsigned short*)d_ws;                      // 8 MB
  unsigned short* wt  = (unsigned short*)((char*)d_ws + 8388608);   // 144 KB
  unsigned short* wot = (unsigned short*)((char*)d_ws + 8536064);   // 36 KB
  float* offs = (float*)((char*)d_ws + 8572928);                    // 4.5 MB

  prep_all<<<872, 256, 0, stream>>>(x, mw, ow, xt, wt, wot);
  offs_mfma<<<1024, 256, 0, stream>>>(xt, wot, ob, offs);
  deform_mfma<<<1024, 256, 0, stream>>>(xt, offs, wt, mb, out);
}